// Round 9
// baseline (189.379 us; speedup 1.0000x reference)
//
#include <hip/hip_runtime.h>
#include <hip/hip_bf16.h>

// GRU cell v9: v8 structure (64-row blocks, 8 waves, wave tile 64x32, 64 KB LDS,
// 2 blocks/CU) but register-allocatable: rolled K-loop (unroll 1, 2 groups/iter,
// named double-buffer), no inline-asm cvt (compiler fuses v_cvt_pk_bf16_f32),
// single shared A-address per group. Weights fragment-major in d_ws.

typedef __attribute__((ext_vector_type(8))) short s8v;           // 8 bf16 = 4 VGPR
typedef __attribute__((ext_vector_type(8))) unsigned short us8;
typedef __attribute__((ext_vector_type(4))) float f32x4;
typedef __attribute__((ext_vector_type(4))) float f4v;

__device__ __forceinline__ float bf2f(unsigned short u) {
  union { unsigned int i; float f; } c; c.i = ((unsigned int)u) << 16; return c.f;
}
__device__ __forceinline__ unsigned short f2bf(float f) {
  __hip_bfloat16 b = __float2bfloat16(f);          // HW RNE; compiler pairs into cvt_pk
  union { __hip_bfloat16 b; unsigned short u; } c; c.b = b; return c.u;
}
__device__ __forceinline__ unsigned int pk2(float lo, float hi) {
  return (unsigned int)f2bf(lo) | ((unsigned int)f2bf(hi) << 16);
}
__device__ __forceinline__ float sig_(float s)  { return 1.0f / (1.0f + __expf(-s)); }
__device__ __forceinline__ float tanh_(float s) { return 2.0f / (1.0f + __expf(-2.0f * s)) - 1.0f; }

// ---------------- weight prep: fp32 [K][N] -> bf16 fragment-major tiles ----------------
// Tile (nt, kt) = 16 n x 32 k = 512 shorts (1 KB), lane-major:
//   n = nt*16 + (lane&15), k = kt*32 + (lane>>4)*8 + e ; tile index t = nt*16 + kt.
// wzr: nt 0..15 = Wz/Uz, nt 16..31 = Wr/Ur (k<256 -> W, else U). whh: nt 0..15 = Wh/Uh.
__global__ void gru_prep(const float* __restrict__ Wz, const float* __restrict__ Uz,
                         const float* __restrict__ Wr, const float* __restrict__ Ur,
                         const float* __restrict__ Wh, const float* __restrict__ Uh,
                         unsigned short* __restrict__ wzr, unsigned short* __restrict__ whh) {
  int idx = blockIdx.x * 256 + threadIdx.x;
  if (idx < 512 * 512) {
    int t = idx >> 9, lane = (idx >> 3) & 63, e = idx & 7;
    int nt = t >> 4, kt = t & 15;
    int n = nt * 16 + (lane & 15);
    int k = kt * 32 + ((lane >> 4) << 3) + e;
    int nn = n & 255;
    float v;
    if (n < 256) v = (k < 256) ? Wz[k * 256 + nn] : Uz[(k - 256) * 256 + nn];
    else         v = (k < 256) ? Wr[k * 256 + nn] : Ur[(k - 256) * 256 + nn];
    wzr[idx] = f2bf(v);
  } else if (idx < 512 * 512 + 256 * 512) {
    int j = idx - 512 * 512;
    int t = j >> 9, lane = (j >> 3) & 63, e = j & 7;
    int nt = t >> 4, kt = t & 15;
    int n = nt * 16 + (lane & 15);
    int k = kt * 32 + ((lane >> 4) << 3) + e;
    float v = (k < 256) ? Wh[k * 256 + n] : Uh[(k - 256) * 256 + n];
    whh[j] = f2bf(v);
  }
}

#define MFMA(a, b, c) __builtin_amdgcn_mfma_f32_16x16x32_bf16((a), (b), (c), 0, 0, 0)

// ---- one K=256 half-sweep: rolled loop, 2 groups/iter, named B double-buffer ----
// Bt = weight base + lane*8. Tiles: group g uses tile g (fb=0) and g+16 tiles (fb=1).
__device__ __forceinline__ void sweep8(f32x4 acc[4][2],
    const unsigned short* __restrict__ Bt,
    const unsigned short* __restrict__ A, int l15, int lg4)
{
  const int r7 = l15 & 7;
  s8v b0a = *(const s8v*)(Bt);
  s8v b1a = *(const s8v*)(Bt + 8192);
#pragma unroll 1
  for (int it = 0; it < 4; ++it) {
    const int g0 = 2 * it;
    // prefetch group g0+1 into B-buffer
    s8v b0b = *(const s8v*)(Bt + (g0 + 1) * 512);
    s8v b1b = *(const s8v*)(Bt + (g0 + 1) * 512 + 8192);
    // ---- group g0 with A-buffer
    {
      const unsigned short* ap = A + l15 * 256 + ((g0 * 4 + lg4) ^ r7) * 8;
      s8v af0 = *(const s8v*)(ap);
      s8v af1 = *(const s8v*)(ap + 16 * 256);
      s8v af2 = *(const s8v*)(ap + 32 * 256);
      s8v af3 = *(const s8v*)(ap + 48 * 256);
      acc[0][0] = MFMA(af0, b0a, acc[0][0]);  acc[0][1] = MFMA(af0, b1a, acc[0][1]);
      acc[1][0] = MFMA(af1, b0a, acc[1][0]);  acc[1][1] = MFMA(af1, b1a, acc[1][1]);
      acc[2][0] = MFMA(af2, b0a, acc[2][0]);  acc[2][1] = MFMA(af2, b1a, acc[2][1]);
      acc[3][0] = MFMA(af3, b0a, acc[3][0]);  acc[3][1] = MFMA(af3, b1a, acc[3][1]);
    }
    // prefetch group g0+2 into A-buffer (skip on last iter)
    if (it < 3) {
      b0a = *(const s8v*)(Bt + (g0 + 2) * 512);
      b1a = *(const s8v*)(Bt + (g0 + 2) * 512 + 8192);
    }
    // ---- group g0+1 with B-buffer
    {
      const unsigned short* ap = A + l15 * 256 + (((g0 + 1) * 4 + lg4) ^ r7) * 8;
      s8v af0 = *(const s8v*)(ap);
      s8v af1 = *(const s8v*)(ap + 16 * 256);
      s8v af2 = *(const s8v*)(ap + 32 * 256);
      s8v af3 = *(const s8v*)(ap + 48 * 256);
      acc[0][0] = MFMA(af0, b0b, acc[0][0]);  acc[0][1] = MFMA(af0, b1b, acc[0][1]);
      acc[1][0] = MFMA(af1, b0b, acc[1][0]);  acc[1][1] = MFMA(af1, b1b, acc[1][1]);
      acc[2][0] = MFMA(af2, b0b, acc[2][0]);  acc[2][1] = MFMA(af2, b1b, acc[2][1]);
      acc[3][0] = MFMA(af3, b0b, acc[3][0]);  acc[3][1] = MFMA(af3, b1b, acc[3][1]);
    }
  }
}

// swizzled scalar LDS accessors (granule-XOR layout, matches sweep8 reads)
__device__ __forceinline__ float ldsA_get(const unsigned short* A, int row, int col) {
  int gp = ((col >> 3) ^ (row & 7));
  return bf2f(A[row * 256 + gp * 8 + (col & 7)]);
}
__device__ __forceinline__ void ldsA_put(unsigned short* A, int row, int col, unsigned short v) {
  int gp = ((col >> 3) ^ (row & 7));
  A[row * 256 + gp * 8 + (col & 7)] = v;
}

// ---------------- main fused kernel: 64 rows per block, 8 waves ----------------
__global__ __launch_bounds__(512, 4) void gru_main(
    const float* __restrict__ x, const float* __restrict__ hp,
    const unsigned short* __restrict__ wzr, const unsigned short* __restrict__ whh,
    const float* __restrict__ bz, const float* __restrict__ br, const float* __restrict__ bh,
    float* __restrict__ out)
{
  __shared__ __align__(16) unsigned short x_l[64 * 256];   // 32 KB, granule-XOR swizzled
  __shared__ __align__(16) unsigned short h_l[64 * 256];   // 32 KB -> 64 KB total

  const int tid = threadIdx.x;
  const int lane = tid & 63;
  const int wv = tid >> 6;                   // 0..7 : wave's 32-col slice
  const int l15 = lane & 15, lg4 = lane >> 4;
  const int blk = blockIdx.x;
  const int row0 = blk * 64;

  const unsigned short* Bz = wzr + wv * 16384 + lane * 8;            // z: nt = wv*2
  const unsigned short* Br = wzr + 131072 + wv * 16384 + lane * 8;   // r: nt = wv*2+16
  const unsigned short* Bh = whh + wv * 16384 + lane * 8;            // h

  // ---- stage x, h tiles to LDS (fp32 -> bf16), granule-XOR layout
  {
    const int srow = tid >> 3;               // 0..63
    const int part = tid & 7;                // 4 granules each
    const float* xs = x  + (size_t)(row0 + srow) * 256 + part * 32;
    const float* hs = hp + (size_t)(row0 + srow) * 256 + part * 32;
    unsigned short* xd = x_l + srow * 256;
    unsigned short* hd = h_l + srow * 256;
    const int r7 = srow & 7;
#pragma unroll
    for (int j = 0; j < 4; ++j) {
      int gp = (part * 4 + j) ^ r7;
      f4v v0 = *(const f4v*)(xs + j * 8);
      f4v v1 = *(const f4v*)(xs + j * 8 + 4);
      us8 o;
      o[0]=f2bf(v0[0]); o[1]=f2bf(v0[1]); o[2]=f2bf(v0[2]); o[3]=f2bf(v0[3]);
      o[4]=f2bf(v1[0]); o[5]=f2bf(v1[1]); o[6]=f2bf(v1[2]); o[7]=f2bf(v1[3]);
      *(us8*)(xd + gp * 8) = o;
    }
#pragma unroll
    for (int j = 0; j < 4; ++j) {
      int gp = (part * 4 + j) ^ r7;
      f4v v0 = *(const f4v*)(hs + j * 8);
      f4v v1 = *(const f4v*)(hs + j * 8 + 4);
      us8 o;
      o[0]=f2bf(v0[0]); o[1]=f2bf(v0[1]); o[2]=f2bf(v0[2]); o[3]=f2bf(v0[3]);
      o[4]=f2bf(v1[0]); o[5]=f2bf(v1[1]); o[6]=f2bf(v1[2]); o[7]=f2bf(v1[3]);
      *(us8*)(hd + gp * 8) = o;
    }
  }
  __syncthreads();

  f32x4 acc[4][2];
  unsigned int zp[4][2][2];    // z gate, packed bf16   : 16 VGPR
  unsigned int rhp[4][2][2];   // r*h_prev, packed bf16 : 16 VGPR

  // ===== PASS z: z = sigmoid(x Wz + h Uz + bz) -> zp
#pragma unroll
  for (int fa = 0; fa < 4; ++fa)
#pragma unroll
    for (int fb = 0; fb < 2; ++fb) acc[fa][fb] = (f32x4){0.f,0.f,0.f,0.f};
  sweep8(acc, Bz,        x_l, l15, lg4);
  sweep8(acc, Bz + 4096, h_l, l15, lg4);     // kt 8..15
#pragma unroll
  for (int fb = 0; fb < 2; ++fb) {
    float bv = bz[wv * 32 + fb * 16 + l15];
#pragma unroll
    for (int fa = 0; fa < 4; ++fa) {
      f32x4 a = acc[fa][fb];
#pragma unroll
      for (int p = 0; p < 2; ++p)
        zp[fa][fb][p] = pk2(sig_(a[2*p] + bv), sig_(a[2*p+1] + bv));
    }
  }

  // ===== PASS r: r = sigmoid(x Wr + h Ur + br); rh = r*h_prev -> rhp
#pragma unroll
  for (int fa = 0; fa < 4; ++fa)
#pragma unroll
    for (int fb = 0; fb < 2; ++fb) acc[fa][fb] = (f32x4){0.f,0.f,0.f,0.f};
  sweep8(acc, Br,        x_l, l15, lg4);
  sweep8(acc, Br + 4096, h_l, l15, lg4);
#pragma unroll
  for (int fb = 0; fb < 2; ++fb) {
    const int col = wv * 32 + fb * 16 + l15;
    const float bv = br[col];
#pragma unroll
    for (int fa = 0; fa < 4; ++fa) {
      f32x4 a = acc[fa][fb];
#pragma unroll
      for (int p = 0; p < 2; ++p) {
        const int row = fa * 16 + lg4 * 4 + 2 * p;
        float r0 = sig_(a[2*p]   + bv);
        float r1 = sig_(a[2*p+1] + bv);
        float h0 = ldsA_get(h_l, row,     col);
        float h1 = ldsA_get(h_l, row + 1, col);
        rhp[fa][fb][p] = pk2(r0 * h0, r1 * h1);
      }
    }
  }

  // ===== PASS h: h_hat = tanh(x Wh + rh Uh + bh)
#pragma unroll
  for (int fa = 0; fa < 4; ++fa)
#pragma unroll
    for (int fb = 0; fb < 2; ++fb) acc[fa][fb] = (f32x4){0.f,0.f,0.f,0.f};
  sweep8(acc, Bh, x_l, l15, lg4);            // x half (x_l still valid)

  __syncthreads();                           // all waves done reading x_l
#pragma unroll
  for (int fb = 0; fb < 2; ++fb) {           // overwrite x_l with rh
    const int col = wv * 32 + fb * 16 + l15;
#pragma unroll
    for (int fa = 0; fa < 4; ++fa)
#pragma unroll
      for (int p = 0; p < 2; ++p) {
        const int row = fa * 16 + lg4 * 4 + 2 * p;
        unsigned int w = rhp[fa][fb][p];
        ldsA_put(x_l, row,     col, (unsigned short)(w & 0xffffu));
        ldsA_put(x_l, row + 1, col, (unsigned short)(w >> 16));
      }
  }
  __syncthreads();                           // rh visible

  sweep8(acc, Bh + 4096, x_l, l15, lg4);     // rh half (kt 8..15)

  // ===== epilogue: h = z*h_prev + (1-z)*h_hat
#pragma unroll
  for (int fb = 0; fb < 2; ++fb) {
    const int col = wv * 32 + fb * 16 + l15;
    const float bv = bh[col];
#pragma unroll
    for (int fa = 0; fa < 4; ++fa) {
      f32x4 a = acc[fa][fb];
#pragma unroll
      for (int i = 0; i < 4; ++i) {
        const int row = fa * 16 + lg4 * 4 + i;
        float hh = tanh_(a[i] + bv);
        unsigned int zw = zp[fa][fb][i >> 1];
        float z = bf2f((unsigned short)((i & 1) ? (zw >> 16) : (zw & 0xffffu)));
        float hv = ldsA_get(h_l, row, col);
        out[(size_t)(row0 + row) * 256 + col] = z * hv + (1.0f - z) * hh;
      }
    }
  }
}

extern "C" void kernel_launch(void* const* d_in, const int* in_sizes, int n_in,
                              void* d_out, int out_size, void* d_ws, size_t ws_size,
                              hipStream_t stream) {
  const float* x  = (const float*)d_in[0];
  const float* hp = (const float*)d_in[1];
  const float* Wz = (const float*)d_in[2];
  const float* Uz = (const float*)d_in[3];
  const float* bz = (const float*)d_in[4];
  const float* Wr = (const float*)d_in[5];
  const float* Ur = (const float*)d_in[6];
  const float* br = (const float*)d_in[7];
  const float* Wh = (const float*)d_in[8];
  const float* Uh = (const float*)d_in[9];
  const float* bh = (const float*)d_in[10];

  if (ws_size < (size_t)(512 * 512 + 256 * 512) * sizeof(unsigned short)) return;  // need 768 KB

  unsigned short* wzr = (unsigned short*)d_ws;
  unsigned short* whh = wzr + 512 * 512;

  gru_prep<<<1536, 256, 0, stream>>>(Wz, Uz, Wr, Ur, Wh, Uh, wzr, whh);
  gru_main<<<1024, 512, 0, stream>>>(x, hp, wzr, whh, bz, br, bh, (float*)d_out);
}

// Round 10
// 137.650 us; speedup vs baseline: 1.3758x; 1.3758x over previous
//
#include <hip/hip_runtime.h>
#include <hip/hip_bf16.h>

// GRU cell v10: v8 structure (64-row blocks, 8 waves, tile 64x32, 64 KB LDS,
// 2 blocks/CU via launch_bounds(512,4)) with zp/rhp offloaded to thread-private
// slots in the block's own d_out region (even-i dwords = z, odd-i = rh; all
// overwritten by final h). Arch-VGPR demand now fits the 64-reg half of the
// 128 unified budget (other 64 = AGPR acc) -> no spills. Full-unroll sweeps
// with distance-1 named B double-buffer + sched_barrier fences.

typedef __attribute__((ext_vector_type(8))) short s8v;           // 8 bf16 = 4 VGPR
typedef __attribute__((ext_vector_type(8))) unsigned short us8;
typedef __attribute__((ext_vector_type(4))) float f32x4;
typedef __attribute__((ext_vector_type(4))) float f4v;

__device__ __forceinline__ float bf2f(unsigned short u) {
  union { unsigned int i; float f; } c; c.i = ((unsigned int)u) << 16; return c.f;
}
__device__ __forceinline__ unsigned short f2bf(float f) {
  union { float f; unsigned int i; } c; c.f = f;
  return (unsigned short)((c.i + 0x7fffu + ((c.i >> 16) & 1u)) >> 16);  // RNE
}
__device__ __forceinline__ unsigned int pk2(float lo, float hi) {
  return (unsigned int)f2bf(lo) | ((unsigned int)f2bf(hi) << 16);
}
__device__ __forceinline__ float sig_(float s)  { return 1.0f / (1.0f + __expf(-s)); }
__device__ __forceinline__ float tanh_(float s) { return 2.0f / (1.0f + __expf(-2.0f * s)) - 1.0f; }

// ---------------- weight prep: fp32 [K][N] -> bf16 fragment-major tiles ----------------
// Tile (nt, kt) = 16 n x 32 k = 512 shorts (1 KB), lane-major:
//   n = nt*16 + (lane&15), k = kt*32 + (lane>>4)*8 + e ; tile index t = nt*16 + kt.
// wzr: nt 0..15 = Wz/Uz, nt 16..31 = Wr/Ur (k<256 -> W, else U). whh: nt 0..15 = Wh/Uh.
__global__ void gru_prep(const float* __restrict__ Wz, const float* __restrict__ Uz,
                         const float* __restrict__ Wr, const float* __restrict__ Ur,
                         const float* __restrict__ Wh, const float* __restrict__ Uh,
                         unsigned short* __restrict__ wzr, unsigned short* __restrict__ whh) {
  int idx = blockIdx.x * 256 + threadIdx.x;
  if (idx < 512 * 512) {
    int t = idx >> 9, lane = (idx >> 3) & 63, e = idx & 7;
    int nt = t >> 4, kt = t & 15;
    int n = nt * 16 + (lane & 15);
    int k = kt * 32 + ((lane >> 4) << 3) + e;
    int nn = n & 255;
    float v;
    if (n < 256) v = (k < 256) ? Wz[k * 256 + nn] : Uz[(k - 256) * 256 + nn];
    else         v = (k < 256) ? Wr[k * 256 + nn] : Ur[(k - 256) * 256 + nn];
    wzr[idx] = f2bf(v);
  } else if (idx < 512 * 512 + 256 * 512) {
    int j = idx - 512 * 512;
    int t = j >> 9, lane = (j >> 3) & 63, e = j & 7;
    int nt = t >> 4, kt = t & 15;
    int n = nt * 16 + (lane & 15);
    int k = kt * 32 + ((lane >> 4) << 3) + e;
    float v = (k < 256) ? Wh[k * 256 + n] : Uh[(k - 256) * 256 + n];
    whh[j] = f2bf(v);
  }
}

#define MFMA(a, b, c) __builtin_amdgcn_mfma_f32_16x16x32_bf16((a), (b), (c), 0, 0, 0)

// ---- one K=256 half-sweep (8 groups, full unroll): B distance-1 double-buffer ----
__device__ __forceinline__ void sweep8(f32x4 acc[4][2],
    const unsigned short* __restrict__ Bt,
    const unsigned short* A, int l15, int lg4)
{
  const int r7 = l15 & 7;
  s8v bb[2][2];
  bb[0][0] = *(const s8v*)(Bt);
  bb[0][1] = *(const s8v*)(Bt + 8192);
#pragma unroll
  for (int g = 0; g < 8; ++g) {
    if (g < 7) {
      bb[(g + 1) & 1][0] = *(const s8v*)(Bt + (g + 1) * 512);
      bb[(g + 1) & 1][1] = *(const s8v*)(Bt + (g + 1) * 512 + 8192);
    }
    __builtin_amdgcn_sched_barrier(0);
    const unsigned short* ap = A + l15 * 256 + ((g * 4 + lg4) ^ r7) * 8;
    s8v af0 = *(const s8v*)(ap);
    s8v af1 = *(const s8v*)(ap + 16 * 256);
    s8v af2 = *(const s8v*)(ap + 32 * 256);
    s8v af3 = *(const s8v*)(ap + 48 * 256);
    acc[0][0] = MFMA(af0, bb[g & 1][0], acc[0][0]);  acc[0][1] = MFMA(af0, bb[g & 1][1], acc[0][1]);
    acc[1][0] = MFMA(af1, bb[g & 1][0], acc[1][0]);  acc[1][1] = MFMA(af1, bb[g & 1][1], acc[1][1]);
    acc[2][0] = MFMA(af2, bb[g & 1][0], acc[2][0]);  acc[2][1] = MFMA(af2, bb[g & 1][1], acc[2][1]);
    acc[3][0] = MFMA(af3, bb[g & 1][0], acc[3][0]);  acc[3][1] = MFMA(af3, bb[g & 1][1], acc[3][1]);
    __builtin_amdgcn_sched_barrier(0);
  }
}

// swizzled scalar LDS accessors (granule-XOR layout, matches sweep8 reads)
__device__ __forceinline__ float ldsA_get(const unsigned short* A, int row, int col) {
  int gp = ((col >> 3) ^ (row & 7));
  return bf2f(A[row * 256 + gp * 8 + (col & 7)]);
}
__device__ __forceinline__ void ldsA_put(unsigned short* A, int row, int col, unsigned short v) {
  int gp = ((col >> 3) ^ (row & 7));
  A[row * 256 + gp * 8 + (col & 7)] = v;
}

// ---------------- main fused kernel: 64 rows per block, 8 waves ----------------
__global__ __launch_bounds__(512, 4) void gru_main(
    const float* __restrict__ x, const float* __restrict__ hp,
    const unsigned short* __restrict__ wzr, const unsigned short* __restrict__ whh,
    const float* __restrict__ bz, const float* __restrict__ br, const float* __restrict__ bh,
    float* __restrict__ out)
{
  __shared__ __align__(16) unsigned short x_l[64 * 256];   // 32 KB, granule-XOR swizzled
  __shared__ __align__(16) unsigned short h_l[64 * 256];   // 32 KB -> 64 KB total

  const int tid = threadIdx.x;
  const int lane = tid & 63;
  const int wv = tid >> 6;                   // 0..7 : wave's 32-col slice
  const int l15 = lane & 15, lg4 = lane >> 4;
  const int blk = blockIdx.x;
  const int row0 = blk * 64;

  const unsigned short* Bz = wzr + wv * 16384 + lane * 8;            // z: nt = wv*2
  const unsigned short* Br = wzr + 131072 + wv * 16384 + lane * 8;   // r: nt = wv*2+16
  const unsigned short* Bh = whh + wv * 16384 + lane * 8;            // h

  unsigned int* outw = (unsigned int*)out;
  // thread-private gate slot: dword address of output element (fa, fb, i)
#define OSLOT(fa, fb, i) ((size_t)(row0 + (fa) * 16 + lg4 * 4 + (i)) * 256 + wv * 32 + (fb) * 16 + l15)

  // ---- stage x, h tiles to LDS (fp32 -> bf16), granule-XOR layout
  {
    const int srow = tid >> 3;               // 0..63
    const int part = tid & 7;                // 4 granules each
    const float* xs = x  + (size_t)(row0 + srow) * 256 + part * 32;
    const float* hs = hp + (size_t)(row0 + srow) * 256 + part * 32;
    unsigned short* xd = x_l + srow * 256;
    unsigned short* hd = h_l + srow * 256;
    const int r7 = srow & 7;
#pragma unroll
    for (int j = 0; j < 4; ++j) {
      int gp = (part * 4 + j) ^ r7;
      f4v v0 = *(const f4v*)(xs + j * 8);
      f4v v1 = *(const f4v*)(xs + j * 8 + 4);
      us8 o;
      o[0]=f2bf(v0[0]); o[1]=f2bf(v0[1]); o[2]=f2bf(v0[2]); o[3]=f2bf(v0[3]);
      o[4]=f2bf(v1[0]); o[5]=f2bf(v1[1]); o[6]=f2bf(v1[2]); o[7]=f2bf(v1[3]);
      *(us8*)(xd + gp * 8) = o;
    }
#pragma unroll
    for (int j = 0; j < 4; ++j) {
      int gp = (part * 4 + j) ^ r7;
      f4v v0 = *(const f4v*)(hs + j * 8);
      f4v v1 = *(const f4v*)(hs + j * 8 + 4);
      us8 o;
      o[0]=f2bf(v0[0]); o[1]=f2bf(v0[1]); o[2]=f2bf(v0[2]); o[3]=f2bf(v0[3]);
      o[4]=f2bf(v1[0]); o[5]=f2bf(v1[1]); o[6]=f2bf(v1[2]); o[7]=f2bf(v1[3]);
      *(us8*)(hd + gp * 8) = o;
    }
  }
  __syncthreads();

  f32x4 acc[4][2];

  // ===== PASS z: z = sigmoid(x Wz + h Uz + bz) -> even-i out slots (packed bf16)
#pragma unroll
  for (int fa = 0; fa < 4; ++fa)
#pragma unroll
    for (int fb = 0; fb < 2; ++fb) acc[fa][fb] = (f32x4){0.f,0.f,0.f,0.f};
  sweep8(acc, Bz,        x_l, l15, lg4);
  sweep8(acc, Bz + 4096, h_l, l15, lg4);     // kt 8..15
#pragma unroll
  for (int fb = 0; fb < 2; ++fb) {
    float bv = bz[wv * 32 + fb * 16 + l15];
#pragma unroll
    for (int fa = 0; fa < 4; ++fa) {
      f32x4 a = acc[fa][fb];
#pragma unroll
      for (int p = 0; p < 2; ++p)
        outw[OSLOT(fa, fb, 2 * p)] = pk2(sig_(a[2*p] + bv), sig_(a[2*p+1] + bv));
    }
  }

  // ===== PASS r: r = sigmoid(x Wr + h Ur + br); rh = r*h_prev -> odd-i out slots
#pragma unroll
  for (int fa = 0; fa < 4; ++fa)
#pragma unroll
    for (int fb = 0; fb < 2; ++fb) acc[fa][fb] = (f32x4){0.f,0.f,0.f,0.f};
  sweep8(acc, Br,        x_l, l15, lg4);
  sweep8(acc, Br + 4096, h_l, l15, lg4);
#pragma unroll
  for (int fb = 0; fb < 2; ++fb) {
    const int col = wv * 32 + fb * 16 + l15;
    const float bv = br[col];
#pragma unroll
    for (int fa = 0; fa < 4; ++fa) {
      f32x4 a = acc[fa][fb];
#pragma unroll
      for (int p = 0; p < 2; ++p) {
        const int row = fa * 16 + lg4 * 4 + 2 * p;
        float r0 = sig_(a[2*p]   + bv);
        float r1 = sig_(a[2*p+1] + bv);
        float h0 = ldsA_get(h_l, row,     col);
        float h1 = ldsA_get(h_l, row + 1, col);
        outw[OSLOT(fa, fb, 2 * p + 1)] = pk2(r0 * h0, r1 * h1);
      }
    }
  }

  // ===== PASS h: h_hat = tanh(x Wh + rh Uh + bh)
#pragma unroll
  for (int fa = 0; fa < 4; ++fa)
#pragma unroll
    for (int fb = 0; fb < 2; ++fb) acc[fa][fb] = (f32x4){0.f,0.f,0.f,0.f};
  sweep8(acc, Bh, x_l, l15, lg4);            // x half (x_l still valid)

  // read back rh words (thread-private, L2-hot); issue before barrier
  unsigned int rhw[4][2][2];
#pragma unroll
  for (int fb = 0; fb < 2; ++fb)
#pragma unroll
    for (int fa = 0; fa < 4; ++fa)
#pragma unroll
      for (int p = 0; p < 2; ++p)
        rhw[fa][fb][p] = outw[OSLOT(fa, fb, 2 * p + 1)];

  __syncthreads();                           // all waves done reading x_l
#pragma unroll
  for (int fb = 0; fb < 2; ++fb) {           // overwrite x_l with rh
    const int col = wv * 32 + fb * 16 + l15;
#pragma unroll
    for (int fa = 0; fa < 4; ++fa)
#pragma unroll
      for (int p = 0; p < 2; ++p) {
        const int row = fa * 16 + lg4 * 4 + 2 * p;
        unsigned int w = rhw[fa][fb][p];
        ldsA_put(x_l, row,     col, (unsigned short)(w & 0xffffu));
        ldsA_put(x_l, row + 1, col, (unsigned short)(w >> 16));
      }
  }
  __syncthreads();                           // rh visible

  sweep8(acc, Bh + 4096, x_l, l15, lg4);     // rh half (kt 8..15)

  // ===== final epilogue: h = z*h_prev + (1-z)*h_hat
  unsigned int zw[4][2][2];                  // hoist all z loads (thread-private slots)
#pragma unroll
  for (int fb = 0; fb < 2; ++fb)
#pragma unroll
    for (int fa = 0; fa < 4; ++fa)
#pragma unroll
      for (int p = 0; p < 2; ++p)
        zw[fa][fb][p] = outw[OSLOT(fa, fb, 2 * p)];
#pragma unroll
  for (int fb = 0; fb < 2; ++fb) {
    const int col = wv * 32 + fb * 16 + l15;
    const float bv = bh[col];
#pragma unroll
    for (int fa = 0; fa < 4; ++fa) {
      f32x4 a = acc[fa][fb];
#pragma unroll
      for (int i = 0; i < 4; ++i) {
        const int row = fa * 16 + lg4 * 4 + i;
        float hh = tanh_(a[i] + bv);
        unsigned int w = zw[fa][fb][i >> 1];
        float z = bf2f((unsigned short)((i & 1) ? (w >> 16) : (w & 0xffffu)));
        float hv = ldsA_get(h_l, row, col);
        out[(size_t)(row0 + row) * 256 + col] = z * hv + (1.0f - z) * hh;
      }
    }
  }
#undef OSLOT
}

extern "C" void kernel_launch(void* const* d_in, const int* in_sizes, int n_in,
                              void* d_out, int out_size, void* d_ws, size_t ws_size,
                              hipStream_t stream) {
  const float* x  = (const float*)d_in[0];
  const float* hp = (const float*)d_in[1];
  const float* Wz = (const float*)d_in[2];
  const float* Uz = (const float*)d_in[3];
  const float* bz = (const float*)d_in[4];
  const float* Wr = (const float*)d_in[5];
  const float* Ur = (const float*)d_in[6];
  const float* br = (const float*)d_in[7];
  const float* Wh = (const float*)d_in[8];
  const float* Uh = (const float*)d_in[9];
  const float* bh = (const float*)d_in[10];

  if (ws_size < (size_t)(512 * 512 + 256 * 512) * sizeof(unsigned short)) return;  // need 768 KB

  unsigned short* wzr = (unsigned short*)d_ws;
  unsigned short* whh = wzr + 512 * 512;

  gru_prep<<<1536, 256, 0, stream>>>(Wz, Uz, Wr, Ur, Wh, Uh, wzr, whh);
  gru_main<<<1024, 512, 0, stream>>>(x, hp, wzr, whh, bz, br, bh, (float*)d_out);
}